// Round 7
// baseline (12335.343 us; speedup 1.0000x reference)
//
#include <hip/hip_runtime.h>

// NeuralODE SIREN (2->128->128->2, sin, w0=44), RK4 3/8-rule, 100 steps.
// Round 9: swap GEMM-2 operands + 32x32x16 MFMA.
//   Z2^T = (SCALE*W2)^T @ H^T : M = h2-dim (4 tiles of 32), N = particles
//   (2 tiles of 32), K = 128 (8 k-steps of 16).
//  - Matrix floor -12%: 192 MFMAs of 32x32x16 (8.07 CU-cyc) vs 384 of
//    16x16x32 (4.85): same 10.3 TFLOP, fewer+fatter ops, half issue slots.
//  - C-layout (m74/m101-verified: col=lane&31 -> PARTICLE, row=(r&3)+8(r>>2)
//    +4(lane>>5) -> h2-dim) makes the n-reduction lane-local: 64 in-lane rows
//    + ONE __shfl_xor(32) + 2 cndmask. Replaces 128 DPP + sel16 (~160 inst).
//    Ownership natural: p = base + lane. Epilogue partials 32->8 floats.
//  - Same 3-term trunc-split numerics (Wh*hh + Wl*hh + Wh*hl), same prep
//    values (W2[k][m]) re-indexed to the 32x32 A-operand layout.
//  - Block-parity k-step stagger anti-phases the 2 co-resident waves.
//  - Keeps: round-6 zero-spill structure, no-fract sin, v_perm packing,
//    setprio around MFMA sweep. Spill canaries: WRITE ~2.13e5 KB, FETCH ~2e3.

#define W0F    44.0f
#define INV2PI 0.15915494309189535f
#define SCALE  (W0F * INV2PI)
#define WIDTH  128
#define NPART  262144
#define TSTEPS 101

typedef short s16x8  __attribute__((ext_vector_type(8)));
typedef float f32x16 __attribute__((ext_vector_type(16)));

__device__ __forceinline__ float sin_rev(float z) {
    // sin(2*pi*z) via v_sin_f32 (revolutions). |z| <= ~55 << +-256 domain.
    return __builtin_amdgcn_sinf(z);
}
__device__ __forceinline__ unsigned short f2bf(float x) {   // RNE f32->bf16
    __bf16 b = (__bf16)x;
    return __builtin_bit_cast(unsigned short, b);
}
__device__ __forceinline__ float bf2f(unsigned short u) {   // exact bf16->f32
    unsigned int v = ((unsigned int)u) << 16;
    return __builtin_bit_cast(float, v);
}
__device__ __forceinline__ float trunc16f(float v) {        // clear low 16 mantissa bits
    return __builtin_bit_cast(float, __builtin_bit_cast(unsigned int, v) & 0xffff0000u);
}
__device__ __forceinline__ unsigned int pack_hi16(float vlo, float vhi) {
    // {top16(vhi) : top16(vlo)} in one v_perm_b32
    return __builtin_amdgcn_perm(__builtin_bit_cast(unsigned int, vhi),
                                 __builtin_bit_cast(unsigned int, vlo),
                                 0x07060302u);
}

// ws layout: shorts [0,16384) = W2T-hi A-frags; shorts [16384,32768) = W2T-lo
// A-frags; floats [16384,16640) = SCALE*W1; floats [16640,16768) = SCALE*b1.
// Frag index i = ((mt*8+ks)*64 + l)*8 + j  <->  A'[row][k] = SCALE*W2[k][row],
// row = 32*mt+(l&31), k = 16*ks+8*(l>>5)+j   (mfma_f32_32x32x16_bf16 A-layout).
__global__ void prep_kernel(const float* __restrict__ W1, const float* __restrict__ b1,
                            const float* __restrict__ W2, float* __restrict__ ws) {
    int i = blockIdx.x * blockDim.x + threadIdx.x;
    unsigned short* whi = (unsigned short*)ws;
    unsigned short* wlo = whi + 16384;
    if (i < 16384) {
        int j = i & 7, l = (i >> 3) & 63, ks = (i >> 9) & 7, mt = (i >> 12) & 3;
        int k = 16 * ks + 8 * (l >> 5) + j;   // h1-dim
        int m = 32 * mt + (l & 31);           // h2-dim (row)
        float v = SCALE * W2[k * WIDTH + m];
        unsigned short hi = f2bf(v);
        whi[i] = hi;
        wlo[i] = f2bf(v - bf2f(hi));
    }
    if (i < 2 * WIDTH) ws[16384 + i] = SCALE * W1[i];
    if (i < WIDTH)     ws[16384 + 256 + i] = SCALE * b1[i];
}

__launch_bounds__(256, 2)
__global__ void ode_kernel(const float* __restrict__ t,
                           const float2* __restrict__ x0,
                           const float* __restrict__ ws,
                           const float* __restrict__ W3,
                           const float* __restrict__ b2,
                           const float* __restrict__ b3,
                           float2* __restrict__ out) {
    __shared__ unsigned int sBh[8192];                    // W2T-hi frags, 32 KB
    __shared__ unsigned int sBl[8192];                    // W2T-lo frags, 32 KB
    __shared__ __align__(16) float sWx[WIDTH], sWy[WIDTH], sWb[WIDTH];
    __shared__ __align__(16) float2 sW3[WIDTH];           // {w3x, w3y}
    __shared__ __align__(16) float  sB2[WIDTH];           // SCALE*b2

    const int tid = threadIdx.x;
    const int wave = tid >> 6;
    const int lane = tid & 63;
    const int lane31 = lane & 31;
    const int h5 = lane >> 5;

    // one-time staging (hi + lo fragment banks)
    {
        const uint4* srch = (const uint4*)ws;
        const uint4* srcl = (const uint4*)(ws + 8192);
        uint4* dsth = (uint4*)sBh;
        uint4* dstl = (uint4*)sBl;
        #pragma unroll
        for (int j = 0; j < 8; ++j) {
            dsth[tid + 256 * j] = srch[tid + 256 * j];
            dstl[tid + 256 * j] = srcl[tid + 256 * j];
        }
    }
    if (tid < WIDTH) {
        sWx[tid] = ws[16384 + tid];
        sWy[tid] = ws[16384 + WIDTH + tid];
        sWb[tid] = ws[16384 + 256 + tid];
        sW3[tid] = make_float2(W3[2 * tid], W3[2 * tid + 1]);
        sB2[tid] = SCALE * b2[tid];
    }
    __syncthreads();   // the ONLY barrier; hot loop is barrier/fence-free

    // Natural ownership: lane owns particle col = 32*h5 + lane31 = lane.
    const int p = blockIdx.x * 256 + wave * 64 + lane;

    float2 y = x0[p];
    out[p] = y;   // row 0 = x0

    const float b30 = b3[0], b31 = b3[1];
    const int ksrot = (blockIdx.x & 1) << 2;   // anti-phase the 2 resident waves

    float tprev = t[0];
    #pragma unroll 1
    for (int step = 0; step < TSTEPS - 1; ++step) {
        const float tnext = t[step + 1];
        const float dt = tnext - tprev;
        tprev = tnext;

        float k1x=0.f,k1y=0.f,k2x=0.f,k2y=0.f,k3x=0.f,k3y=0.f,sx=0.f,sy=0.f;

        #pragma unroll 1
        for (int s = 0; s < 4; ++s) {
            float yinx, yiny;
            if (s == 0)      { yinx = y.x;                                 yiny = y.y; }
            else if (s == 1) { const float c1 = dt * (1.0f / 3.0f);
                               yinx = y.x + c1 * k1x;                       yiny = y.y + c1 * k1y; }
            else if (s == 2) { yinx = y.x + dt * (k2x - (1.0f/3.0f) * k1x); yiny = y.y + dt * (k2y - (1.0f/3.0f) * k1y); }
            else             { yinx = y.x + dt * (k1x - k2x + k3x);         yiny = y.y + dt * (k1y - k2y + k3y); }

            // ---- f(yin) ----
            // B-operand cols are particles: col = 32*n + lane31.
            const float qx0 = __shfl(yinx, lane31,      64);
            const float qy0 = __shfl(yiny, lane31,      64);
            const float qx1 = __shfl(yinx, lane31 + 32, 64);
            const float qy1 = __shfl(yiny, lane31 + 32, 64);

            // acc[4 m-tiles][2 n-tiles] of f32x16 = 128 AGPRs.
            // Element r: row = 32*mt + (r&3) + 8*(r>>2) + 4*h5, col = 32*n+lane31.
            // Init = SCALE*b2[row].
            f32x16 acc[4][2];
            #pragma unroll
            for (int mt = 0; mt < 4; ++mt) {
                #pragma unroll
                for (int g = 0; g < 4; ++g) {
                    float4 bb = *(const float4*)&sB2[32 * mt + 8 * g + 4 * h5];
                    acc[mt][0][4*g+0] = bb.x; acc[mt][0][4*g+1] = bb.y;
                    acc[mt][0][4*g+2] = bb.z; acc[mt][0][4*g+3] = bb.w;
                    acc[mt][1][4*g+0] = bb.x; acc[mt][1][4*g+1] = bb.y;
                    acc[mt][1][4*g+2] = bb.z; acc[mt][1][4*g+3] = bb.w;
                }
            }

            #pragma unroll 1
            for (int kk = 0; kk < 8; ++kk) {
                const int ks = (kk + ksrot) & 7;
                // Build B-frags (h values, trunc split): element j of frag n is
                // B[k=16ks+8h5+j][col=32n+lane31] = sin(q.x*W1x[k]+q.y*W1y[k]+b1[k]).
                uint4 bh0, bh1, bl0, bl1;
                #pragma unroll
                for (int jq = 0; jq < 2; ++jq) {
                    float4 wxv = *(const float4*)&sWx[16 * ks + 8 * h5 + 4 * jq];
                    float4 wyv = *(const float4*)&sWy[16 * ks + 8 * h5 + 4 * jq];
                    float4 wbv = *(const float4*)&sWb[16 * ks + 8 * h5 + 4 * jq];
                    #pragma unroll
                    for (int n = 0; n < 2; ++n) {
                        const float qxm = n ? qx1 : qx0;
                        const float qym = n ? qy1 : qy0;
                        float v0 = sin_rev(fmaf(qxm, wxv.x, fmaf(qym, wyv.x, wbv.x)));
                        float v1 = sin_rev(fmaf(qxm, wxv.y, fmaf(qym, wyv.y, wbv.y)));
                        float v2 = sin_rev(fmaf(qxm, wxv.z, fmaf(qym, wyv.z, wbv.z)));
                        float v3 = sin_rev(fmaf(qxm, wxv.w, fmaf(qym, wyv.w, wbv.w)));
                        float r0 = v0 - trunc16f(v0);
                        float r1 = v1 - trunc16f(v1);
                        float r2 = v2 - trunc16f(v2);
                        float r3 = v3 - trunc16f(v3);
                        unsigned int hA = pack_hi16(v0, v1), hB = pack_hi16(v2, v3);
                        unsigned int lA = pack_hi16(r0, r1), lB = pack_hi16(r2, r3);
                        if (n == 0) {
                            if (jq == 0) { bh0.x = hA; bh0.y = hB; bl0.x = lA; bl0.y = lB; }
                            else         { bh0.z = hA; bh0.w = hB; bl0.z = lA; bl0.w = lB; }
                        } else {
                            if (jq == 0) { bh1.x = hA; bh1.y = hB; bl1.x = lA; bl1.y = lB; }
                            else         { bh1.z = hA; bh1.w = hB; bl1.z = lA; bl1.w = lB; }
                        }
                    }
                }
                s16x8 vbh0 = __builtin_bit_cast(s16x8, bh0);
                s16x8 vbh1 = __builtin_bit_cast(s16x8, bh1);
                s16x8 vbl0 = __builtin_bit_cast(s16x8, bl0);
                s16x8 vbl1 = __builtin_bit_cast(s16x8, bl1);

                // MFMA sweep: A = W2T frags from LDS (hi+lo), 24 MFMAs.
                __builtin_amdgcn_s_setprio(1);
                #pragma unroll
                for (int mt = 0; mt < 4; ++mt) {
                    const int fo = (mt * 8 + ks) * 256 + lane * 4;
                    uint4 ahU = *(const uint4*)&sBh[fo];
                    uint4 alU = *(const uint4*)&sBl[fo];
                    s16x8 ah = __builtin_bit_cast(s16x8, ahU);
                    s16x8 al = __builtin_bit_cast(s16x8, alU);
                    acc[mt][0] = __builtin_amdgcn_mfma_f32_32x32x16_bf16(ah, vbh0, acc[mt][0], 0, 0, 0);
                    acc[mt][0] = __builtin_amdgcn_mfma_f32_32x32x16_bf16(al, vbh0, acc[mt][0], 0, 0, 0);
                    acc[mt][0] = __builtin_amdgcn_mfma_f32_32x32x16_bf16(ah, vbl0, acc[mt][0], 0, 0, 0);
                    acc[mt][1] = __builtin_amdgcn_mfma_f32_32x32x16_bf16(ah, vbh1, acc[mt][1], 0, 0, 0);
                    acc[mt][1] = __builtin_amdgcn_mfma_f32_32x32x16_bf16(al, vbh1, acc[mt][1], 0, 0, 0);
                    acc[mt][1] = __builtin_amdgcn_mfma_f32_32x32x16_bf16(ah, vbl1, acc[mt][1], 0, 0, 0);
                }
                __builtin_amdgcn_s_setprio(0);
            }

            // Epilogue: sn = sin(z2); partial f per n-tile, summed over the
            // 64 in-lane h2-rows; chains split by g-parity.
            float px0[2] = {0.f, 0.f}, py0[2] = {0.f, 0.f};
            float px1[2] = {0.f, 0.f}, py1[2] = {0.f, 0.f};
            #pragma unroll
            for (int mt = 0; mt < 4; ++mt) {
                #pragma unroll
                for (int g = 0; g < 4; ++g) {
                    const float4* w3p = (const float4*)&sW3[32 * mt + 8 * g + 4 * h5];
                    float4 wA = w3p[0];   // rows +0,+1: {x0,y0,x1,y1}
                    float4 wB = w3p[1];   // rows +2,+3
                    #pragma unroll
                    for (int q = 0; q < 4; ++q) {
                        const float w3x = (q == 0) ? wA.x : (q == 1) ? wA.z : (q == 2) ? wB.x : wB.z;
                        const float w3y = (q == 0) ? wA.y : (q == 1) ? wA.w : (q == 2) ? wB.y : wB.w;
                        float s0 = sin_rev(acc[mt][0][4*g+q]);
                        float s1 = sin_rev(acc[mt][1][4*g+q]);
                        px0[g & 1] = fmaf(s0, w3x, px0[g & 1]);
                        py0[g & 1] = fmaf(s0, w3y, py0[g & 1]);
                        px1[g & 1] = fmaf(s1, w3x, px1[g & 1]);
                        py1[g & 1] = fmaf(s1, w3y, py1[g & 1]);
                    }
                }
            }
            const float gx0 = px0[0] + px0[1], gy0 = py0[0] + py0[1];
            const float gx1 = px1[0] + px1[1], gy1 = py1[0] + py1[1];
            // Cross-half reduction: my rows cover offset 4*h5; partner (lane^32)
            // covers the other half. own = g[n=h5]; send = g[1-h5] (what the
            // partner needs for ITS n).
            const float ownx = h5 ? gx1 : gx0, sndx = h5 ? gx0 : gx1;
            const float owny = h5 ? gy1 : gy0, sndy = h5 ? gy0 : gy1;
            const float fx = b30 + ownx + __shfl_xor(sndx, 32, 64);
            const float fy = b31 + owny + __shfl_xor(sndy, 32, 64);
            // ---- end f ----

            if (s == 0)      { k1x = fx; k1y = fy; sx = fx;        sy = fy; }
            else if (s == 1) { k2x = fx; k2y = fy; sx += 3.f * fx; sy += 3.f * fy; }
            else if (s == 2) { k3x = fx; k3y = fy; sx += 3.f * fx; sy += 3.f * fy; }
            else             {                     sx += fx;       sy += fy; }
        }

        const float cc = dt * 0.125f;
        y.x += sx * cc;
        y.y += sy * cc;
        out[(size_t)(step + 1) * NPART + p] = y;
    }
}

extern "C" void kernel_launch(void* const* d_in, const int* in_sizes, int n_in,
                              void* d_out, int out_size, void* d_ws, size_t ws_size,
                              hipStream_t stream) {
    const float*  t  = (const float*)d_in[0];
    const float2* x0 = (const float2*)d_in[1];
    const float*  W1 = (const float*)d_in[2];
    const float*  b1 = (const float*)d_in[3];
    const float*  W2 = (const float*)d_in[4];
    const float*  b2 = (const float*)d_in[5];
    const float*  W3 = (const float*)d_in[6];
    const float*  b3 = (const float*)d_in[7];
    float* ws = (float*)d_ws;
    float2* out = (float2*)d_out;

    prep_kernel<<<64, 256, 0, stream>>>(W1, b1, W2, ws);
    ode_kernel<<<NPART / 256, 256, 0, stream>>>(t, x0, ws, W3, b2, b3, out);
}